// Round 5
// baseline (181.258 us; speedup 1.0000x reference)
//
#include <hip/hip_runtime.h>

#define NN 24
#define POWER_ITERS 30
#define FISTA_ITERS 200

typedef float v2f __attribute__((ext_vector_type(2)));
typedef float v4f __attribute__((ext_vector_type(4)));

__device__ __forceinline__ v2f fma2(v2f a, v2f b, v2f c) {
    return __builtin_elementwise_fma(a, b, c);
}

// 8-lane-group broadcast: every lane reads the value held by lane (group_base | ML).
// ds_swizzle BitMode offset = (xor<<10)|(or<<5)|and ; and=0x18 keeps the 8-group base.
template<int ML>
__device__ __forceinline__ float bc8(float v) {
    return __int_as_float(__builtin_amdgcn_ds_swizzle(__float_as_int(v), (ML << 5) | 0x18));
}
// XOR butterflies for 8-lane reductions
__device__ __forceinline__ float gx1(float v) {
    return __int_as_float(__builtin_amdgcn_ds_swizzle(__float_as_int(v), 0x041F));
}
__device__ __forceinline__ float gx2(float v) {
    return __int_as_float(__builtin_amdgcn_ds_swizzle(__float_as_int(v), 0x081F));
}
__device__ __forceinline__ float gx4(float v) {
    return __int_as_float(__builtin_amdgcn_ds_swizzle(__float_as_int(v), 0x101F));
}

// Fused all-gather + matvec, swizzle-only (no LDS, no barriers).
// Distribution: y[j] j<8 -> lane j slot s0 ; y[8+2c+e] -> lane c slot s1/s2.
// Pairs feed v_pk_fma_f32 against float2-packed G rows.
#define PKSTEP(p_, e0_, e1_)                                                   \
    { const v2f yp_ = (v2f){(e0_), (e1_)};                                     \
      a0_ = fma2(G0[p_], yp_, a0_);                                            \
      a1_ = fma2(G1[p_], yp_, a1_);                                            \
      a2_ = fma2(G2[p_], yp_, a2_); }
#define MATVEC_SWZ(s0, s1, s2, b0_, b1_, b2_, g0_, g1_, g2_) do {              \
    v2f a0_ = (v2f){(b0_), 0.f};                                               \
    v2f a1_ = (v2f){(b1_), 0.f};                                               \
    v2f a2_ = (v2f){(b2_), 0.f};                                               \
    PKSTEP(0,  bc8<0>(s0), bc8<1>(s0))                                         \
    PKSTEP(1,  bc8<2>(s0), bc8<3>(s0))                                         \
    PKSTEP(2,  bc8<4>(s0), bc8<5>(s0))                                         \
    PKSTEP(3,  bc8<6>(s0), bc8<7>(s0))                                         \
    PKSTEP(4,  bc8<0>(s1), bc8<0>(s2))                                         \
    PKSTEP(5,  bc8<1>(s1), bc8<1>(s2))                                         \
    PKSTEP(6,  bc8<2>(s1), bc8<2>(s2))                                         \
    PKSTEP(7,  bc8<3>(s1), bc8<3>(s2))                                         \
    PKSTEP(8,  bc8<4>(s1), bc8<4>(s2))                                         \
    PKSTEP(9,  bc8<5>(s1), bc8<5>(s2))                                         \
    PKSTEP(10, bc8<6>(s1), bc8<6>(s2))                                         \
    PKSTEP(11, bc8<7>(s1), bc8<7>(s2))                                         \
    g0_ = a0_.x + a0_.y; g1_ = a1_.x + a1_.y; g2_ = a2_.x + a2_.y;             \
} while (0)

__global__ __attribute__((amdgpu_waves_per_eu(4, 4))) void __launch_bounds__(256)
qcqp_kernel(const float* __restrict__ P, const float* __restrict__ qv,
            float* __restrict__ out, int Btot) {
    const int tid = blockIdx.x * blockDim.x + threadIdx.x;
    const int b = tid >> 3;
    if (b >= Btot) return;
    const int ls = tid & 7;       // lane-in-group; owns cone ls
    const int rx = 8 + 2 * ls;    // global rows {ls, rx, rx+1}

    const float* __restrict__ Pb = P + (size_t)b * (NN * NN);
    const float* __restrict__ qb = qv + (size_t)b * NN;

    // ---- Phase 1: own 3 rows of G = P^T P (REG=1e-7 dropped: ~3e-8 rel),
    //      bb = -(P^T q) own rows. Rows held as 12 float2 pairs each. ----
    v2f G0[12], G1[12], G2[12];
#pragma unroll
    for (int p = 0; p < 12; ++p) {
        G0[p] = (v2f){0.f, 0.f}; G1[p] = (v2f){0.f, 0.f}; G2[p] = (v2f){0.f, 0.f};
    }
    float bb0 = 0.f, bb1 = 0.f, bb2 = 0.f;

#pragma unroll 1
    for (int k = 0; k < NN; ++k) {
        const float* rp = Pb + k * NN;
        v2f row2[12];
#pragma unroll
        for (int m = 0; m < 6; ++m) {
            const v4f r = *reinterpret_cast<const v4f*>(rp + 4 * m);
            row2[2 * m]     = (v2f){r.x, r.y};
            row2[2 * m + 1] = (v2f){r.z, r.w};
        }
        const float  a0 = rp[ls];
        const float2 ax = *reinterpret_cast<const float2*>(rp + rx);
        const float  qk = qb[k];
        bb0 = fmaf(-a0,   qk, bb0);
        bb1 = fmaf(-ax.x, qk, bb1);
        bb2 = fmaf(-ax.y, qk, bb2);
        const v2f a0s = (v2f){a0, a0};
        const v2f a1s = (v2f){ax.x, ax.x};
        const v2f a2s = (v2f){ax.y, ax.y};
#pragma unroll
        for (int p = 0; p < 12; ++p) {
            G0[p] = fma2(a0s, row2[p], G0[p]);
            G1[p] = fma2(a1s, row2[p], G1[p]);
            G2[p] = fma2(a2s, row2[p], G2[p]);
        }
    }

    // ---- Phase 2: power iteration -> step = 1/(L + 1e-12) ----
    float vo0 = 0.20412414523193150818f;  // 1/sqrt(24)
    float vo1 = vo0, vo2 = vo0;

#pragma unroll 1
    for (int it = 0; it < POWER_ITERS; ++it) {
        float g0, g1, g2;
        MATVEC_SWZ(vo0, vo1, vo2, 0.f, 0.f, 0.f, g0, g1, g2);
        float n2 = g0 * g0 + g1 * g1 + g2 * g2;
        n2 += gx1(n2);
        n2 += gx2(n2);
        n2 += gx4(n2);
        const float inv = __builtin_amdgcn_rsqf(fmaxf(n2, 1e-60f));
        vo0 = g0 * inv; vo1 = g1 * inv; vo2 = g2 * inv;
    }
    float step;
    {
        float g0, g1, g2;
        MATVEC_SWZ(vo0, vo1, vo2, 0.f, 0.f, 0.f, g0, g1, g2);
        float Lp = vo0 * g0 + vo1 * g1 + vo2 * g2;
        Lp += gx1(Lp);
        Lp += gx2(Lp);
        Lp += gx4(Lp);
        step = __builtin_amdgcn_rcpf(Lp + 1e-12f);
    }
    const float nstep = -step;

    // ---- Phase 3: FISTA ----
    float yo0 = 0.f, yo1 = 0.f, yo2 = 0.f;
    float lo0 = 0.f, lo1 = 0.f, lo2 = 0.f;
    float tk = 1.f;

#pragma unroll 1
    for (int it = 0; it < FISTA_ITERS; ++it) {
        float g0, g1, g2;
        MATVEC_SWZ(yo0, yo1, yo2, bb0, bb1, bb2, g0, g1, g2);
        const float t  = fmaf(nstep, g0, yo0);
        const float x1 = fmaf(nstep, g1, yo1);
        const float x2 = fmaf(nstep, g2, yo2);
        // SOC projection (lane-local: lane owns exactly cone ls)
        const float nx    = __builtin_amdgcn_sqrtf(fmaf(x1, x1, x2 * x2));
        const float alpha = 0.5f * (t + nx);
        const bool inside = (nx <= t);
        const bool zero_  = (nx <= -t);
        const float ln0 = inside ? t : (zero_ ? 0.f : alpha);
        const float sc  = inside ? 1.f
                                 : (zero_ ? 0.f
                                          : alpha * __builtin_amdgcn_rcpf(fmaxf(nx, 1e-12f)));
        const float ln1 = x1 * sc;
        const float ln2 = x2 * sc;
        const float tkn = 0.5f * (1.f + __builtin_amdgcn_sqrtf(fmaf(4.f * tk, tk, 1.f)));
        const float bet = (tk - 1.f) * __builtin_amdgcn_rcpf(tkn);
        tk = tkn;
        yo0 = fmaf(bet, ln0 - lo0, ln0);
        yo1 = fmaf(bet, ln1 - lo1, ln1);
        yo2 = fmaf(bet, ln2 - lo2, ln2);
        lo0 = ln0; lo1 = ln1; lo2 = ln2;
    }

    // ---- store own components (disjoint across the group, covers all 24) ----
    float* ob = out + (size_t)b * NN;
    ob[ls] = lo0;
    *reinterpret_cast<v2f*>(ob + rx) = (v2f){lo1, lo2};
}

extern "C" void kernel_launch(void* const* d_in, const int* in_sizes, int n_in,
                              void* d_out, int out_size, void* d_ws, size_t ws_size,
                              hipStream_t stream) {
    const float* P = (const float*)d_in[0];
    const float* q = (const float*)d_in[1];
    float* out = (float*)d_out;
    const int Btot = in_sizes[0] / (NN * NN);
    const long long threads = 8LL * Btot;
    const int block = 256;
    const int grid = (int)((threads + block - 1) / block);
    qcqp_kernel<<<grid, block, 0, stream>>>(P, q, out, Btot);
}